// Round 16
// baseline (84.692 us; speedup 1.0000x reference)
//
#include <hip/hip_runtime.h>

typedef __attribute__((ext_vector_type(2))) long long2v;
typedef __attribute__((ext_vector_type(4))) float f32x4;

#define EPSV 1e-5f
// (1/TEMP) * log2(e),  TEMP = 0.5  -> exp2-domain scale
#define SCALE 2.885390081777927f

// Must be the builtin — raw inline-asm v_exp_f32 lacks the TRANS-pipe hazard
// nop (asm is opaque to the hazard recognizer) and returns garbage (R4).
__device__ __forceinline__ float fast_exp2(float x) { return __builtin_amdgcn_exp2f(x); }

// f32 -> OCP e4m3fn byte (hardware converter; saturates at +-448)
__device__ __forceinline__ unsigned char f32_to_fp8(float f) {
  return (unsigned char)(__builtin_amdgcn_cvt_pk_fp8_f32(f, f, 0, false) & 0xff);
}

// ---------------------------------------------------------------------------
// FP8 packed bank layout (pre-scaled by SCALE), unchanged from R14:
//   quarter q (2 KB) = (ct = q>>1, qK = q&1); lane (kg,r16) reads 16 B at
//   q*2048 + pair*1024 + kg*256 + r16*16 holding B-frags ks=2*pair, 2*pair+1.
// Apk (fp8 anchors): byte = p*16384 + row*256 + k.
// ---------------------------------------------------------------------------

// ---------------------------------------------------------------------------
// Fused prep kernel, grid = 512 + 512 + 64 = 1088 blocks, 256 threads.
// ---------------------------------------------------------------------------
__global__ __launch_bounds__(256) void cpl_prep(
    const float* __restrict__ mainO, const float* __restrict__ emaO,
    const float* __restrict__ label, const float* __restrict__ negB,
    const float* __restrict__ posB,
    unsigned char* __restrict__ Apk, float* __restrict__ posDot,
    int* __restrict__ flags, unsigned char* __restrict__ bankN,
    unsigned char* __restrict__ bankP)
{
  __shared__ __align__(16) unsigned char shU[64 * 256];   // 16 KiB
  __shared__ float shF[4][64];
  const int bid = blockIdx.x;
  const int t = threadIdx.x;

  if (bid < 512) {
    // ---- anchor pack (fp8) + pos dot: block = (b, y) ----
    const int b = bid >> 6, y = bid & 63;
    const int cg = t >> 4;            // c-offset 0..15
    const int x4 = t & 15;            // float4 index along W
    const float* mB = mainO + (((size_t)b * 256 + cg) * 64 + y) * 64 + x4 * 4;
    const float* eB = emaO  + (((size_t)b * 256 + cg) * 64 + y) * 64 + x4 * 4;
    float4 acc4 = make_float4(0.f, 0.f, 0.f, 0.f);
#pragma unroll
    for (int pass = 0; pass < 16; ++pass) {
      const int c = pass * 16 + cg;
      const float4 mv = *(const float4*)(mB + (size_t)pass * 16 * 4096);
      const float4 ev = *(const float4*)(eB + (size_t)pass * 16 * 4096);
      acc4.x += mv.x * ev.x; acc4.y += mv.y * ev.y;
      acc4.z += mv.z * ev.z; acc4.w += mv.w * ev.w;
      const float vals[4] = {mv.x, mv.y, mv.z, mv.w};
#pragma unroll
      for (int j = 0; j < 4; ++j) {
        const int x = x4 * 4 + j;
        shU[x * 256 + (c ^ ((x & 7) << 4))] = f32_to_fp8(vals[j]);
      }
    }
    // reduce pos partials over c-groups (cg bit0 = lane bit4, bit1 = lane bit5)
    acc4.x += __shfl_xor(acc4.x, 16, 64); acc4.y += __shfl_xor(acc4.y, 16, 64);
    acc4.z += __shfl_xor(acc4.z, 16, 64); acc4.w += __shfl_xor(acc4.w, 16, 64);
    acc4.x += __shfl_xor(acc4.x, 32, 64); acc4.y += __shfl_xor(acc4.y, 32, 64);
    acc4.z += __shfl_xor(acc4.z, 32, 64); acc4.w += __shfl_xor(acc4.w, 32, 64);
    if ((t & 63) < 16) *(float4*)&shF[t >> 6][(t & 15) * 4] = acc4;
    __syncthreads();
    // write packed fp8 anchors (coalesced b128)
#pragma unroll
    for (int it = 0; it < 4; ++it) {
      const int lin = it * 256 + t;          // 0..1023
      const int x = lin >> 4, c16 = lin & 15;
      const uint4 v = *(const uint4*)&shU[x * 256 + ((c16 * 16) ^ ((x & 7) << 4))];
      const int p = b * 64 + ((y >> 3) << 3) + (x >> 3);
      const int n = ((y & 7) << 3) + (x & 7);
      *(uint4*)&Apk[(size_t)p * 16384 + n * 256 + c16 * 16] = v;
    }
    if (t < 64) {
      const float pv = shF[0][t] + shF[1][t] + shF[2][t] + shF[3][t];
      const int p = b * 64 + ((y >> 3) << 3) + (t >> 3);
      const int n = ((y & 7) << 3) + (t & 7);
      posDot[p * 64 + n] = pv;
    }
  } else if (bid < 1024) {
    // ---- label mean -> flag ----
    const int p = bid - 512;
    const int b = p >> 6, pj = (p >> 3) & 7, pk = p & 7;
    const size_t base = ((size_t)b * 256 + pj * 32) * 256 + pk * 32;
    float s = 0.f;
#pragma unroll
    for (int i = 0; i < 4; ++i) {
      const int e = t * 4 + i;               // 0..1023, r=e>>5, cc=e&31
      s += label[base + (size_t)(e >> 5) * 256 + (e & 31)];
    }
#pragma unroll
    for (int d = 1; d < 64; d <<= 1) s += __shfl_xor(s, d, 64);
    if ((t & 63) == 0) shF[0][t >> 6] = s;
    __syncthreads();
    if (t == 0)
      flags[p] = ((shF[0][0] + shF[0][1] + shF[0][2] + shF[0][3]) * (1.f / 1024.f) < 0.1f) ? 1 : 0;
  } else {
    // ---- bank repack (fp8, pre-scaled by SCALE) into packed tile layout ----
    const int bb = bid - 1024;
    const float* src = (bb < 32 ? negB : posB) + (size_t)(bb & 31) * 16384;
    unsigned char* dst = (bb < 32 ? bankN : bankP) + (size_t)(bb & 31) * 16384;
#pragma unroll 8
    for (int it = 0; it < 64; ++it) {
      const int lin = it * 256 + t;          // [c][posi] linear, coalesced read
      const int c = lin >> 6, posi = lin & 63;
      shU[posi * 256 + (c ^ ((posi & 7) << 3))] = f32_to_fp8(src[lin] * SCALE);
    }
    __syncthreads();
#pragma unroll
    for (int it = 0; it < 4; ++it) {         // ct_local = it
      const int qK = (t >> 7) & 1, pair = (t >> 6) & 1;
      const int kg = (t >> 4) & 3, r16 = t & 15;
      const int posi = it * 16 + r16;
      const int kb = qK * 128 + pair * 64 + kg * 8;
      const int swz = (posi & 7) << 3;
      const unsigned long long lo = *(const unsigned long long*)&shU[posi * 256 + (kb ^ swz)];
      const unsigned long long hi = *(const unsigned long long*)&shU[posi * 256 + ((kb + 32) ^ swz)];
      long2v v; v[0] = (long)lo; v[1] = (long)hi;
      *(long2v*)(dst + it * 4096 + qK * 2048 + pair * 1024 + kg * 256 + r16 * 16) = v;
    }
  }
}

// ---------------------------------------------------------------------------
// Main kernel: grid=512 (one patch), block=256 (4 independent waves), FP8.
// R14 structure with the register ring deepened 8 -> 12 quarters (22 loads
// in flight per wave, 44/SIMD): the R13/R14 data shows the step is
// latency-exposure-bound (1125 cy vs 745-cy staging floor), so delivered
// B/cy scales with in-flight depth. 2 waves/SIMD preserved (VGPR ~233).
// ---------------------------------------------------------------------------
__global__ __launch_bounds__(256, 2) void cpl_main(
    const unsigned char* __restrict__ Apk, const float* __restrict__ posDot,
    const unsigned char* __restrict__ bankN, const unsigned char* __restrict__ bankP,
    const int* __restrict__ flags, float* __restrict__ blockSums)
{
  __shared__ float swS[4][64];

  const int p = blockIdx.x;
  const int t = threadIdx.x;
  const int l = t & 63, w = t >> 6;
  const int r16 = l & 15, kg = l >> 4;
  const int qph = (p * 22) & 63;      // EVEN phase: preserves quarter parity

  const unsigned char* bankB = flags[p] ? bankP : bankN;
  const unsigned char* wsrc = bankB + (size_t)w * 131072 + kg * 256 + r16 * 16;

  // ---- A fragments (fp8): lane l holds A[mt*16+r16][ks*32+kg*8 .. +7] ----
  const unsigned char* Ab = Apk + (size_t)p * 16384;
  long long afrag[4][8];
#pragma unroll
  for (int mt = 0; mt < 4; ++mt)
#pragma unroll
    for (int ks = 0; ks < 8; ++ks)
      afrag[mt][ks] = *(const long long*)(Ab + (mt * 16 + r16) * 256 + ks * 32 + kg * 8);
#pragma unroll
  for (int mt = 0; mt < 4; ++mt)
#pragma unroll
    for (int ks = 0; ks < 8; ++ks)
      asm volatile("" : "+v"(afrag[mt][ks]));

  // per-lane -pos2 init in REGISTERS (row = mt*16 + kg*4 + i)
  f32x4 negInit[4];
#pragma unroll
  for (int mt = 0; mt < 4; ++mt) {
    f32x4 v = *(const f32x4*)(posDot + (size_t)p * 64 + mt * 16 + kg * 4);
#pragma unroll
    for (int i = 0; i < 4; ++i) negInit[mt][i] = -v[i] * SCALE;
  }
#pragma unroll
  for (int mt = 0; mt < 4; ++mt) asm volatile("" : "+v"(negInit[mt]));

  float s[16];
#pragma unroll
  for (int e = 0; e < 16; ++e) s[e] = 0.f;

  f32x4 acc[4];
  long2v A0, A1, B0, B1, C0, C1, D0, D1, E0, E1, F0, F1,
         G0, G1, H0, H1, I0, I1, J0, J1, K0, K1, L0, L1;

#define GLOAD(P0, P1, QQ) do {                                                     \
    const unsigned char* g_ = wsrc + (size_t)((((QQ) + qph) & 63)) * 2048;         \
    P0 = *(const long2v*)g_;                                                       \
    P1 = *(const long2v*)(g_ + 1024);                                              \
  } while (0)

#define MFMA16(P0, P1, HALF) do {                                                  \
    if ((HALF) == 0) {                                                             \
      _Pragma("unroll") for (int mt = 0; mt < 4; ++mt)                             \
        acc[mt] = __builtin_amdgcn_mfma_f32_16x16x32_fp8_fp8(afrag[mt][0], P0[0],  \
                      negInit[mt], 0, 0, 0);                                       \
      _Pragma("unroll") for (int mt = 0; mt < 4; ++mt)                             \
        acc[mt] = __builtin_amdgcn_mfma_f32_16x16x32_fp8_fp8(afrag[mt][1], P0[1],  \
                      acc[mt], 0, 0, 0);                                           \
      _Pragma("unroll") for (int mt = 0; mt < 4; ++mt)                             \
        acc[mt] = __builtin_amdgcn_mfma_f32_16x16x32_fp8_fp8(afrag[mt][2], P1[0],  \
                      acc[mt], 0, 0, 0);                                           \
      _Pragma("unroll") for (int mt = 0; mt < 4; ++mt)                             \
        acc[mt] = __builtin_amdgcn_mfma_f32_16x16x32_fp8_fp8(afrag[mt][3], P1[1],  \
                      acc[mt], 0, 0, 0);                                           \
    } else {                                                                       \
      _Pragma("unroll") for (int mt = 0; mt < 4; ++mt)                             \
        acc[mt] = __builtin_amdgcn_mfma_f32_16x16x32_fp8_fp8(afrag[mt][4], P0[0],  \
                      acc[mt], 0, 0, 0);                                           \
      _Pragma("unroll") for (int mt = 0; mt < 4; ++mt)                             \
        acc[mt] = __builtin_amdgcn_mfma_f32_16x16x32_fp8_fp8(afrag[mt][5], P0[1],  \
                      acc[mt], 0, 0, 0);                                           \
      _Pragma("unroll") for (int mt = 0; mt < 4; ++mt)                             \
        acc[mt] = __builtin_amdgcn_mfma_f32_16x16x32_fp8_fp8(afrag[mt][6], P1[0],  \
                      acc[mt], 0, 0, 0);                                           \
      _Pragma("unroll") for (int mt = 0; mt < 4; ++mt)                             \
        acc[mt] = __builtin_amdgcn_mfma_f32_16x16x32_fp8_fp8(afrag[mt][7], P1[1],  \
                      acc[mt], 0, 0, 0);                                           \
    } } while (0)

#define EXPACC() do {                                                              \
    _Pragma("unroll") for (int mt = 0; mt < 4; ++mt)                               \
      _Pragma("unroll") for (int i = 0; i < 4; ++i)                                \
        s[mt * 4 + i] += fast_exp2(acc[mt][i]); } while (0)

  // STEP n: load quarter n+11 into the buffer freed last step; MFMA on the
  // buffer loaded 11 steps ago (compiler emits counted vmcnt); EXP after odd.
#define STEP(QQ, U0, U1, L0_, L1_, HALF, DO_LOAD, DO_EXP) do {                     \
    if (DO_LOAD) GLOAD(L0_, L1_, (QQ) + 11);                                       \
    __builtin_amdgcn_sched_barrier(0);                                             \
    __builtin_amdgcn_s_setprio(1);                                                 \
    MFMA16(U0, U1, HALF);                                                          \
    __builtin_amdgcn_s_setprio(0);                                                 \
    if (DO_EXP) EXPACC();                                                          \
    __builtin_amdgcn_sched_barrier(0);                                             \
  } while (0)

#define GROUP12(n0) do {                                                           \
    STEP(n0 + 0,  A0, A1, L0, L1, 0, 1, 0);                                        \
    STEP(n0 + 1,  B0, B1, A0, A1, 1, 1, 1);                                        \
    STEP(n0 + 2,  C0, C1, B0, B1, 0, 1, 0);                                        \
    STEP(n0 + 3,  D0, D1, C0, C1, 1, 1, 1);                                        \
    STEP(n0 + 4,  E0, E1, D0, D1, 0, 1, 0);                                        \
    STEP(n0 + 5,  F0, F1, E0, E1, 1, 1, 1);                                        \
    STEP(n0 + 6,  G0, G1, F0, F1, 0, 1, 0);                                        \
    STEP(n0 + 7,  H0, H1, G0, G1, 1, 1, 1);                                        \
    STEP(n0 + 8,  I0, I1, H0, H1, 0, 1, 0);                                        \
    STEP(n0 + 9,  J0, J1, I0, I1, 1, 1, 1);                                        \
    STEP(n0 + 10, K0, K1, J0, J1, 0, 1, 0);                                        \
    STEP(n0 + 11, L0, L1, K0, K1, 1, 1, 1);                                        \
  } while (0)

  // prologue: quarters 0..10 in flight (22 loads)
  GLOAD(A0, A1, 0); GLOAD(B0, B1, 1); GLOAD(C0, C1, 2); GLOAD(D0, D1, 3);
  GLOAD(E0, E1, 4); GLOAD(F0, F1, 5); GLOAD(G0, G1, 6); GLOAD(H0, H1, 7);
  GLOAD(I0, I1, 8); GLOAD(J0, J1, 9); GLOAD(K0, K1, 10);

  GROUP12(0);
  GROUP12(12);
  GROUP12(24);
  GROUP12(36);
  // group 4: steps 48..59 — loads stop after quarter 63 (step 52)
  STEP(48, A0, A1, L0, L1, 0, 1, 0);   // loads q59
  STEP(49, B0, B1, A0, A1, 1, 1, 1);   // loads q60
  STEP(50, C0, C1, B0, B1, 0, 1, 0);   // loads q61
  STEP(51, D0, D1, C0, C1, 1, 1, 1);   // loads q62
  STEP(52, E0, E1, D0, D1, 0, 1, 0);   // loads q63
  STEP(53, F0, F1, E0, E1, 1, 0, 1);
  STEP(54, G0, G1, F0, F1, 0, 0, 0);
  STEP(55, H0, H1, G0, G1, 1, 0, 1);
  STEP(56, I0, I1, H0, H1, 0, 0, 0);
  STEP(57, J0, J1, I0, I1, 1, 0, 1);
  STEP(58, K0, K1, J0, J1, 0, 0, 0);
  STEP(59, L0, L1, K0, K1, 1, 0, 1);
  // drain: quarters 60..63 live in A..D
  STEP(60, A0, A1, A0, A1, 0, 0, 0);
  STEP(61, B0, B1, B0, B1, 1, 0, 1);
  STEP(62, C0, C1, C0, C1, 0, 0, 0);
  STEP(63, D0, D1, D0, D1, 1, 0, 1);

#undef GROUP12
#undef STEP
#undef EXPACC
#undef MFMA16
#undef GLOAD

  // ---- sum the 16 column-partials (lanes differing in low 4 bits) ----
#pragma unroll
  for (int d = 1; d < 16; d <<= 1)
#pragma unroll
    for (int e = 0; e < 16; ++e) s[e] += __shfl_xor(s[e], d, 64);
  if (r16 == 0) {
#pragma unroll
    for (int mt = 0; mt < 4; ++mt)
#pragma unroll
      for (int i = 0; i < 4; ++i)
        swS[w][mt * 16 + kg * 4 + i] = s[mt * 4 + i];
  }
  __syncthreads();

  // ---- final per-row loss + block reduce (wave 0 only) ----
  if (t < 64) {
    const float S = 1.f + swS[0][t] + swS[1][t] + swS[2][t] + swS[3][t];
    float loss = -logf(1.f / S + EPSV);
#pragma unroll
    for (int d = 1; d < 64; d <<= 1) loss += __shfl_xor(loss, d, 64);
    if (t == 0) blockSums[p] = loss;
  }
}

// ---------------------------------------------------------------------------
// Final: mean of 512 block sums / (512*64).  grid=1, block=256.
// ---------------------------------------------------------------------------
__global__ void cpl_final(const float* __restrict__ blockSums, float* __restrict__ out) {
  const int t = threadIdx.x;
  float s = blockSums[t] + blockSums[t + 256];
#pragma unroll
  for (int d = 1; d < 64; d <<= 1) s += __shfl_xor(s, d, 64);
  __shared__ float ps[4];
  if ((t & 63) == 0) ps[t >> 6] = s;
  __syncthreads();
  if (t == 0) out[0] = (ps[0] + ps[1] + ps[2] + ps[3]) * (1.f / 32768.f);
}

extern "C" void kernel_launch(void* const* d_in, const int* in_sizes, int n_in,
                              void* d_out, int out_size, void* d_ws, size_t ws_size,
                              hipStream_t stream) {
  const float* mainO = (const float*)d_in[0];
  const float* emaO  = (const float*)d_in[1];
  const float* label = (const float*)d_in[2];
  const float* negB  = (const float*)d_in[3];
  const float* posB  = (const float*)d_in[4];
  float* out = (float*)d_out;

  char* ws = (char*)d_ws;
  float*         blockSums = (float*)ws;                          // 2 KiB
  int*           flags     = (int*)(ws + 2048);                   // 2 KiB
  unsigned char* bankN     = (unsigned char*)(ws + 4096);         // 512 KiB
  unsigned char* bankP     = (unsigned char*)(ws + 528384);       // 512 KiB
  float*         posDot    = (float*)(ws + 1052672);              // 128 KiB
  unsigned char* Apk       = (unsigned char*)(ws + 1183744);      // 8 MiB

  hipLaunchKernelGGL(cpl_prep, dim3(1088), dim3(256), 0, stream,
                     mainO, emaO, label, negB, posB, Apk, posDot, flags, bankN, bankP);
  hipLaunchKernelGGL(cpl_main, dim3(512), dim3(256), 0, stream,
                     Apk, posDot, bankN, bankP, flags, blockSums);
  hipLaunchKernelGGL(cpl_final, dim3(1), dim3(256), 0, stream, blockSums, out);
}

// Round 17
// 84.651 us; speedup vs baseline: 1.0005x; 1.0005x over previous
//
#include <hip/hip_runtime.h>

typedef __attribute__((ext_vector_type(2))) long long2v;
typedef __attribute__((ext_vector_type(4))) float f32x4;

#define EPSV 1e-5f
// (1/TEMP) * log2(e),  TEMP = 0.5  -> exp2-domain scale
#define SCALE 2.885390081777927f

// Must be the builtin — raw inline-asm v_exp_f32 lacks the TRANS-pipe hazard
// nop (asm is opaque to the hazard recognizer) and returns garbage (R4).
__device__ __forceinline__ float fast_exp2(float x) { return __builtin_amdgcn_exp2f(x); }

// f32 -> OCP e4m3fn byte (hardware converter; saturates at +-448)
__device__ __forceinline__ unsigned char f32_to_fp8(float f) {
  return (unsigned char)(__builtin_amdgcn_cvt_pk_fp8_f32(f, f, 0, false) & 0xff);
}

// ---------------------------------------------------------------------------
// FP8 packed bank layout (pre-scaled by SCALE), unchanged from R14:
//   quarter q (2 KB) = (ct = q>>1, qK = q&1); lane (kg,r16) reads 16 B at
//   q*2048 + pair*1024 + kg*256 + r16*16 holding B-frags ks=2*pair, 2*pair+1.
// Apk (fp8 anchors): byte = p*16384 + row*256 + k.
// ---------------------------------------------------------------------------

// ---------------------------------------------------------------------------
// Fused prep kernel, grid = 512 + 512 + 64 = 1088 blocks, 256 threads.
// ---------------------------------------------------------------------------
__global__ __launch_bounds__(256) void cpl_prep(
    const float* __restrict__ mainO, const float* __restrict__ emaO,
    const float* __restrict__ label, const float* __restrict__ negB,
    const float* __restrict__ posB,
    unsigned char* __restrict__ Apk, float* __restrict__ posDot,
    int* __restrict__ flags, unsigned char* __restrict__ bankN,
    unsigned char* __restrict__ bankP)
{
  __shared__ __align__(16) unsigned char shU[64 * 256];   // 16 KiB
  __shared__ float shF[4][64];
  const int bid = blockIdx.x;
  const int t = threadIdx.x;

  if (bid < 512) {
    // ---- anchor pack (fp8) + pos dot: block = (b, y) ----
    const int b = bid >> 6, y = bid & 63;
    const int cg = t >> 4;            // c-offset 0..15
    const int x4 = t & 15;            // float4 index along W
    const float* mB = mainO + (((size_t)b * 256 + cg) * 64 + y) * 64 + x4 * 4;
    const float* eB = emaO  + (((size_t)b * 256 + cg) * 64 + y) * 64 + x4 * 4;
    float4 acc4 = make_float4(0.f, 0.f, 0.f, 0.f);
#pragma unroll
    for (int pass = 0; pass < 16; ++pass) {
      const int c = pass * 16 + cg;
      const float4 mv = *(const float4*)(mB + (size_t)pass * 16 * 4096);
      const float4 ev = *(const float4*)(eB + (size_t)pass * 16 * 4096);
      acc4.x += mv.x * ev.x; acc4.y += mv.y * ev.y;
      acc4.z += mv.z * ev.z; acc4.w += mv.w * ev.w;
      const float vals[4] = {mv.x, mv.y, mv.z, mv.w};
#pragma unroll
      for (int j = 0; j < 4; ++j) {
        const int x = x4 * 4 + j;
        shU[x * 256 + (c ^ ((x & 7) << 4))] = f32_to_fp8(vals[j]);
      }
    }
    // reduce pos partials over c-groups (cg bit0 = lane bit4, bit1 = lane bit5)
    acc4.x += __shfl_xor(acc4.x, 16, 64); acc4.y += __shfl_xor(acc4.y, 16, 64);
    acc4.z += __shfl_xor(acc4.z, 16, 64); acc4.w += __shfl_xor(acc4.w, 16, 64);
    acc4.x += __shfl_xor(acc4.x, 32, 64); acc4.y += __shfl_xor(acc4.y, 32, 64);
    acc4.z += __shfl_xor(acc4.z, 32, 64); acc4.w += __shfl_xor(acc4.w, 32, 64);
    if ((t & 63) < 16) *(float4*)&shF[t >> 6][(t & 15) * 4] = acc4;
    __syncthreads();
    // write packed fp8 anchors (coalesced b128)
#pragma unroll
    for (int it = 0; it < 4; ++it) {
      const int lin = it * 256 + t;          // 0..1023
      const int x = lin >> 4, c16 = lin & 15;
      const uint4 v = *(const uint4*)&shU[x * 256 + ((c16 * 16) ^ ((x & 7) << 4))];
      const int p = b * 64 + ((y >> 3) << 3) + (x >> 3);
      const int n = ((y & 7) << 3) + (x & 7);
      *(uint4*)&Apk[(size_t)p * 16384 + n * 256 + c16 * 16] = v;
    }
    if (t < 64) {
      const float pv = shF[0][t] + shF[1][t] + shF[2][t] + shF[3][t];
      const int p = b * 64 + ((y >> 3) << 3) + (t >> 3);
      const int n = ((y & 7) << 3) + (t & 7);
      posDot[p * 64 + n] = pv;
    }
  } else if (bid < 1024) {
    // ---- label mean -> flag ----
    const int p = bid - 512;
    const int b = p >> 6, pj = (p >> 3) & 7, pk = p & 7;
    const size_t base = ((size_t)b * 256 + pj * 32) * 256 + pk * 32;
    float s = 0.f;
#pragma unroll
    for (int i = 0; i < 4; ++i) {
      const int e = t * 4 + i;               // 0..1023, r=e>>5, cc=e&31
      s += label[base + (size_t)(e >> 5) * 256 + (e & 31)];
    }
#pragma unroll
    for (int d = 1; d < 64; d <<= 1) s += __shfl_xor(s, d, 64);
    if ((t & 63) == 0) shF[0][t >> 6] = s;
    __syncthreads();
    if (t == 0)
      flags[p] = ((shF[0][0] + shF[0][1] + shF[0][2] + shF[0][3]) * (1.f / 1024.f) < 0.1f) ? 1 : 0;
  } else {
    // ---- bank repack (fp8, pre-scaled by SCALE) into packed tile layout ----
    const int bb = bid - 1024;
    const float* src = (bb < 32 ? negB : posB) + (size_t)(bb & 31) * 16384;
    unsigned char* dst = (bb < 32 ? bankN : bankP) + (size_t)(bb & 31) * 16384;
#pragma unroll 8
    for (int it = 0; it < 64; ++it) {
      const int lin = it * 256 + t;          // [c][posi] linear, coalesced read
      const int c = lin >> 6, posi = lin & 63;
      shU[posi * 256 + (c ^ ((posi & 7) << 3))] = f32_to_fp8(src[lin] * SCALE);
    }
    __syncthreads();
#pragma unroll
    for (int it = 0; it < 4; ++it) {         // ct_local = it
      const int qK = (t >> 7) & 1, pair = (t >> 6) & 1;
      const int kg = (t >> 4) & 3, r16 = t & 15;
      const int posi = it * 16 + r16;
      const int kb = qK * 128 + pair * 64 + kg * 8;
      const int swz = (posi & 7) << 3;
      const unsigned long long lo = *(const unsigned long long*)&shU[posi * 256 + (kb ^ swz)];
      const unsigned long long hi = *(const unsigned long long*)&shU[posi * 256 + ((kb + 32) ^ swz)];
      long2v v; v[0] = (long)lo; v[1] = (long)hi;
      *(long2v*)(dst + it * 4096 + qK * 2048 + pair * 1024 + kg * 256 + r16 * 16) = v;
    }
  }
}

// ---------------------------------------------------------------------------
// Main kernel: grid=512 (one patch), block=256 (4 independent waves), FP8.
// R16's 12-deep register ring (22 loads in flight/wave) with the register
// allocator PINNED at 2 waves/EU via amdgpu_waves_per_eu(2,2): launch_bounds'
// 2nd arg is only a MINIMUM — the backend still targeted 4 waves/SIMD (128
// VGPRs) in R16 and spilled 95 regs of ring to scratch (WRITE_SIZE 116 MB).
// Pinning min=max=2 gives the 256-reg budget the ring needs (~223 used).
// ---------------------------------------------------------------------------
__global__ __launch_bounds__(256)
__attribute__((amdgpu_waves_per_eu(2, 2)))
void cpl_main(
    const unsigned char* __restrict__ Apk, const float* __restrict__ posDot,
    const unsigned char* __restrict__ bankN, const unsigned char* __restrict__ bankP,
    const int* __restrict__ flags, float* __restrict__ blockSums)
{
  __shared__ float swS[4][64];

  const int p = blockIdx.x;
  const int t = threadIdx.x;
  const int l = t & 63, w = t >> 6;
  const int r16 = l & 15, kg = l >> 4;
  const int qph = (p * 22) & 63;      // EVEN phase: preserves quarter parity

  const unsigned char* bankB = flags[p] ? bankP : bankN;
  const unsigned char* wsrc = bankB + (size_t)w * 131072 + kg * 256 + r16 * 16;

  // ---- A fragments (fp8): lane l holds A[mt*16+r16][ks*32+kg*8 .. +7] ----
  const unsigned char* Ab = Apk + (size_t)p * 16384;
  long long afrag[4][8];
#pragma unroll
  for (int mt = 0; mt < 4; ++mt)
#pragma unroll
    for (int ks = 0; ks < 8; ++ks)
      afrag[mt][ks] = *(const long long*)(Ab + (mt * 16 + r16) * 256 + ks * 32 + kg * 8);
#pragma unroll
  for (int mt = 0; mt < 4; ++mt)
#pragma unroll
    for (int ks = 0; ks < 8; ++ks)
      asm volatile("" : "+v"(afrag[mt][ks]));

  // per-lane -pos2 init in REGISTERS (row = mt*16 + kg*4 + i)
  f32x4 negInit[4];
#pragma unroll
  for (int mt = 0; mt < 4; ++mt) {
    f32x4 v = *(const f32x4*)(posDot + (size_t)p * 64 + mt * 16 + kg * 4);
#pragma unroll
    for (int i = 0; i < 4; ++i) negInit[mt][i] = -v[i] * SCALE;
  }
#pragma unroll
  for (int mt = 0; mt < 4; ++mt) asm volatile("" : "+v"(negInit[mt]));

  float s[16];
#pragma unroll
  for (int e = 0; e < 16; ++e) s[e] = 0.f;

  f32x4 acc[4];
  long2v A0, A1, B0, B1, C0, C1, D0, D1, E0, E1, F0, F1,
         G0, G1, H0, H1, I0, I1, J0, J1, K0, K1, L0, L1;

#define GLOAD(P0, P1, QQ) do {                                                     \
    const unsigned char* g_ = wsrc + (size_t)((((QQ) + qph) & 63)) * 2048;         \
    P0 = *(const long2v*)g_;                                                       \
    P1 = *(const long2v*)(g_ + 1024);                                              \
  } while (0)

#define MFMA16(P0, P1, HALF) do {                                                  \
    if ((HALF) == 0) {                                                             \
      _Pragma("unroll") for (int mt = 0; mt < 4; ++mt)                             \
        acc[mt] = __builtin_amdgcn_mfma_f32_16x16x32_fp8_fp8(afrag[mt][0], P0[0],  \
                      negInit[mt], 0, 0, 0);                                       \
      _Pragma("unroll") for (int mt = 0; mt < 4; ++mt)                             \
        acc[mt] = __builtin_amdgcn_mfma_f32_16x16x32_fp8_fp8(afrag[mt][1], P0[1],  \
                      acc[mt], 0, 0, 0);                                           \
      _Pragma("unroll") for (int mt = 0; mt < 4; ++mt)                             \
        acc[mt] = __builtin_amdgcn_mfma_f32_16x16x32_fp8_fp8(afrag[mt][2], P1[0],  \
                      acc[mt], 0, 0, 0);                                           \
      _Pragma("unroll") for (int mt = 0; mt < 4; ++mt)                             \
        acc[mt] = __builtin_amdgcn_mfma_f32_16x16x32_fp8_fp8(afrag[mt][3], P1[1],  \
                      acc[mt], 0, 0, 0);                                           \
    } else {                                                                       \
      _Pragma("unroll") for (int mt = 0; mt < 4; ++mt)                             \
        acc[mt] = __builtin_amdgcn_mfma_f32_16x16x32_fp8_fp8(afrag[mt][4], P0[0],  \
                      acc[mt], 0, 0, 0);                                           \
      _Pragma("unroll") for (int mt = 0; mt < 4; ++mt)                             \
        acc[mt] = __builtin_amdgcn_mfma_f32_16x16x32_fp8_fp8(afrag[mt][5], P0[1],  \
                      acc[mt], 0, 0, 0);                                           \
      _Pragma("unroll") for (int mt = 0; mt < 4; ++mt)                             \
        acc[mt] = __builtin_amdgcn_mfma_f32_16x16x32_fp8_fp8(afrag[mt][6], P1[0],  \
                      acc[mt], 0, 0, 0);                                           \
      _Pragma("unroll") for (int mt = 0; mt < 4; ++mt)                             \
        acc[mt] = __builtin_amdgcn_mfma_f32_16x16x32_fp8_fp8(afrag[mt][7], P1[1],  \
                      acc[mt], 0, 0, 0);                                           \
    } } while (0)

#define EXPACC() do {                                                              \
    _Pragma("unroll") for (int mt = 0; mt < 4; ++mt)                               \
      _Pragma("unroll") for (int i = 0; i < 4; ++i)                                \
        s[mt * 4 + i] += fast_exp2(acc[mt][i]); } while (0)

  // STEP n: load quarter n+11 into the buffer freed last step; MFMA on the
  // buffer loaded 11 steps ago (compiler emits counted vmcnt); EXP after odd.
#define STEP(QQ, U0, U1, L0_, L1_, HALF, DO_LOAD, DO_EXP) do {                     \
    if (DO_LOAD) GLOAD(L0_, L1_, (QQ) + 11);                                       \
    __builtin_amdgcn_sched_barrier(0);                                             \
    __builtin_amdgcn_s_setprio(1);                                                 \
    MFMA16(U0, U1, HALF);                                                          \
    __builtin_amdgcn_s_setprio(0);                                                 \
    if (DO_EXP) EXPACC();                                                          \
    __builtin_amdgcn_sched_barrier(0);                                             \
  } while (0)

#define GROUP12(n0) do {                                                           \
    STEP(n0 + 0,  A0, A1, L0, L1, 0, 1, 0);                                        \
    STEP(n0 + 1,  B0, B1, A0, A1, 1, 1, 1);                                        \
    STEP(n0 + 2,  C0, C1, B0, B1, 0, 1, 0);                                        \
    STEP(n0 + 3,  D0, D1, C0, C1, 1, 1, 1);                                        \
    STEP(n0 + 4,  E0, E1, D0, D1, 0, 1, 0);                                        \
    STEP(n0 + 5,  F0, F1, E0, E1, 1, 1, 1);                                        \
    STEP(n0 + 6,  G0, G1, F0, F1, 0, 1, 0);                                        \
    STEP(n0 + 7,  H0, H1, G0, G1, 1, 1, 1);                                        \
    STEP(n0 + 8,  I0, I1, H0, H1, 0, 1, 0);                                        \
    STEP(n0 + 9,  J0, J1, I0, I1, 1, 1, 1);                                        \
    STEP(n0 + 10, K0, K1, J0, J1, 0, 1, 0);                                        \
    STEP(n0 + 11, L0, L1, K0, K1, 1, 1, 1);                                        \
  } while (0)

  // prologue: quarters 0..10 in flight (22 loads)
  GLOAD(A0, A1, 0); GLOAD(B0, B1, 1); GLOAD(C0, C1, 2); GLOAD(D0, D1, 3);
  GLOAD(E0, E1, 4); GLOAD(F0, F1, 5); GLOAD(G0, G1, 6); GLOAD(H0, H1, 7);
  GLOAD(I0, I1, 8); GLOAD(J0, J1, 9); GLOAD(K0, K1, 10);

  GROUP12(0);
  GROUP12(12);
  GROUP12(24);
  GROUP12(36);
  // group 4: steps 48..59 — loads stop after quarter 63 (step 52)
  STEP(48, A0, A1, L0, L1, 0, 1, 0);   // loads q59
  STEP(49, B0, B1, A0, A1, 1, 1, 1);   // loads q60
  STEP(50, C0, C1, B0, B1, 0, 1, 0);   // loads q61
  STEP(51, D0, D1, C0, C1, 1, 1, 1);   // loads q62
  STEP(52, E0, E1, D0, D1, 0, 1, 0);   // loads q63
  STEP(53, F0, F1, E0, E1, 1, 0, 1);
  STEP(54, G0, G1, F0, F1, 0, 0, 0);
  STEP(55, H0, H1, G0, G1, 1, 0, 1);
  STEP(56, I0, I1, H0, H1, 0, 0, 0);
  STEP(57, J0, J1, I0, I1, 1, 0, 1);
  STEP(58, K0, K1, J0, J1, 0, 0, 0);
  STEP(59, L0, L1, K0, K1, 1, 0, 1);
  // drain: quarters 60..63 live in A..D
  STEP(60, A0, A1, A0, A1, 0, 0, 0);
  STEP(61, B0, B1, B0, B1, 1, 0, 1);
  STEP(62, C0, C1, C0, C1, 0, 0, 0);
  STEP(63, D0, D1, D0, D1, 1, 0, 1);

#undef GROUP12
#undef STEP
#undef EXPACC
#undef MFMA16
#undef GLOAD

  // ---- sum the 16 column-partials (lanes differing in low 4 bits) ----
#pragma unroll
  for (int d = 1; d < 16; d <<= 1)
#pragma unroll
    for (int e = 0; e < 16; ++e) s[e] += __shfl_xor(s[e], d, 64);
  if (r16 == 0) {
#pragma unroll
    for (int mt = 0; mt < 4; ++mt)
#pragma unroll
      for (int i = 0; i < 4; ++i)
        swS[w][mt * 16 + kg * 4 + i] = s[mt * 4 + i];
  }
  __syncthreads();

  // ---- final per-row loss + block reduce (wave 0 only) ----
  if (t < 64) {
    const float S = 1.f + swS[0][t] + swS[1][t] + swS[2][t] + swS[3][t];
    float loss = -logf(1.f / S + EPSV);
#pragma unroll
    for (int d = 1; d < 64; d <<= 1) loss += __shfl_xor(loss, d, 64);
    if (t == 0) blockSums[p] = loss;
  }
}

// ---------------------------------------------------------------------------
// Final: mean of 512 block sums / (512*64).  grid=1, block=256.
// ---------------------------------------------------------------------------
__global__ void cpl_final(const float* __restrict__ blockSums, float* __restrict__ out) {
  const int t = threadIdx.x;
  float s = blockSums[t] + blockSums[t + 256];
#pragma unroll
  for (int d = 1; d < 64; d <<= 1) s += __shfl_xor(s, d, 64);
  __shared__ float ps[4];
  if ((t & 63) == 0) ps[t >> 6] = s;
  __syncthreads();
  if (t == 0) out[0] = (ps[0] + ps[1] + ps[2] + ps[3]) * (1.f / 32768.f);
}

extern "C" void kernel_launch(void* const* d_in, const int* in_sizes, int n_in,
                              void* d_out, int out_size, void* d_ws, size_t ws_size,
                              hipStream_t stream) {
  const float* mainO = (const float*)d_in[0];
  const float* emaO  = (const float*)d_in[1];
  const float* label = (const float*)d_in[2];
  const float* negB  = (const float*)d_in[3];
  const float* posB  = (const float*)d_in[4];
  float* out = (float*)d_out;

  char* ws = (char*)d_ws;
  float*         blockSums = (float*)ws;                          // 2 KiB
  int*           flags     = (int*)(ws + 2048);                   // 2 KiB
  unsigned char* bankN     = (unsigned char*)(ws + 4096);         // 512 KiB
  unsigned char* bankP     = (unsigned char*)(ws + 528384);       // 512 KiB
  float*         posDot    = (float*)(ws + 1052672);              // 128 KiB
  unsigned char* Apk       = (unsigned char*)(ws + 1183744);      // 8 MiB

  hipLaunchKernelGGL(cpl_prep, dim3(1088), dim3(256), 0, stream,
                     mainO, emaO, label, negB, posB, Apk, posDot, flags, bankN, bankP);
  hipLaunchKernelGGL(cpl_main, dim3(512), dim3(256), 0, stream,
                     Apk, posDot, bankN, bankP, flags, blockSums);
  hipLaunchKernelGGL(cpl_final, dim3(1), dim3(256), 0, stream, blockSums, out);
}

// Round 18
// 53.010 us; speedup vs baseline: 1.5977x; 1.5969x over previous
//
#include <hip/hip_runtime.h>

typedef __attribute__((ext_vector_type(2))) long long2v;
typedef __attribute__((ext_vector_type(4))) float f32x4;

#define EPSV 1e-5f
// (1/TEMP) * log2(e),  TEMP = 0.5  -> exp2-domain scale
#define SCALE 2.885390081777927f

// Must be the builtin — raw inline-asm v_exp_f32 lacks the TRANS-pipe hazard
// nop (asm is opaque to the hazard recognizer) and returns garbage (R4).
__device__ __forceinline__ float fast_exp2(float x) { return __builtin_amdgcn_exp2f(x); }

// f32 -> OCP e4m3fn byte (hardware converter; saturates at +-448)
__device__ __forceinline__ unsigned char f32_to_fp8(float f) {
  return (unsigned char)(__builtin_amdgcn_cvt_pk_fp8_f32(f, f, 0, false) & 0xff);
}

// async global->LDS DMA, 16 B per lane; LDS dest = uniform base + lane*16.
__device__ __forceinline__ void dma16(const void* g, void* l) {
  __builtin_amdgcn_global_load_lds(
      (const __attribute__((address_space(1))) unsigned*)g,
      (__attribute__((address_space(3))) unsigned*)l, 16, 0, 0);
}

// ---------------------------------------------------------------------------
// FP8 packed bank layout (pre-scaled by SCALE), unchanged from R14:
//   quarter q (2 KB) = (ct = q>>1, qK = q&1); lane (kg,r16) reads 16 B at
//   q*2048 + pair*1024 + kg*256 + r16*16 holding B-frags ks=2*pair, 2*pair+1.
// Apk (fp8 anchors): byte = p*16384 + row*256 + k.
// ---------------------------------------------------------------------------

// ---------------------------------------------------------------------------
// Fused prep kernel, grid = 512 + 512 + 64 = 1088 blocks, 256 threads.
// ---------------------------------------------------------------------------
__global__ __launch_bounds__(256) void cpl_prep(
    const float* __restrict__ mainO, const float* __restrict__ emaO,
    const float* __restrict__ label, const float* __restrict__ negB,
    const float* __restrict__ posB,
    unsigned char* __restrict__ Apk, float* __restrict__ posDot,
    int* __restrict__ flags, unsigned char* __restrict__ bankN,
    unsigned char* __restrict__ bankP)
{
  __shared__ __align__(16) unsigned char shU[64 * 256];   // 16 KiB
  __shared__ float shF[4][64];
  const int bid = blockIdx.x;
  const int t = threadIdx.x;

  if (bid < 512) {
    // ---- anchor pack (fp8) + pos dot: block = (b, y) ----
    const int b = bid >> 6, y = bid & 63;
    const int cg = t >> 4;            // c-offset 0..15
    const int x4 = t & 15;            // float4 index along W
    const float* mB = mainO + (((size_t)b * 256 + cg) * 64 + y) * 64 + x4 * 4;
    const float* eB = emaO  + (((size_t)b * 256 + cg) * 64 + y) * 64 + x4 * 4;
    float4 acc4 = make_float4(0.f, 0.f, 0.f, 0.f);
#pragma unroll
    for (int pass = 0; pass < 16; ++pass) {
      const int c = pass * 16 + cg;
      const float4 mv = *(const float4*)(mB + (size_t)pass * 16 * 4096);
      const float4 ev = *(const float4*)(eB + (size_t)pass * 16 * 4096);
      acc4.x += mv.x * ev.x; acc4.y += mv.y * ev.y;
      acc4.z += mv.z * ev.z; acc4.w += mv.w * ev.w;
      const float vals[4] = {mv.x, mv.y, mv.z, mv.w};
#pragma unroll
      for (int j = 0; j < 4; ++j) {
        const int x = x4 * 4 + j;
        shU[x * 256 + (c ^ ((x & 7) << 4))] = f32_to_fp8(vals[j]);
      }
    }
    // reduce pos partials over c-groups (cg bit0 = lane bit4, bit1 = lane bit5)
    acc4.x += __shfl_xor(acc4.x, 16, 64); acc4.y += __shfl_xor(acc4.y, 16, 64);
    acc4.z += __shfl_xor(acc4.z, 16, 64); acc4.w += __shfl_xor(acc4.w, 16, 64);
    acc4.x += __shfl_xor(acc4.x, 32, 64); acc4.y += __shfl_xor(acc4.y, 32, 64);
    acc4.z += __shfl_xor(acc4.z, 32, 64); acc4.w += __shfl_xor(acc4.w, 32, 64);
    if ((t & 63) < 16) *(float4*)&shF[t >> 6][(t & 15) * 4] = acc4;
    __syncthreads();
    // write packed fp8 anchors (coalesced b128)
#pragma unroll
    for (int it = 0; it < 4; ++it) {
      const int lin = it * 256 + t;          // 0..1023
      const int x = lin >> 4, c16 = lin & 15;
      const uint4 v = *(const uint4*)&shU[x * 256 + ((c16 * 16) ^ ((x & 7) << 4))];
      const int p = b * 64 + ((y >> 3) << 3) + (x >> 3);
      const int n = ((y & 7) << 3) + (x & 7);
      *(uint4*)&Apk[(size_t)p * 16384 + n * 256 + c16 * 16] = v;
    }
    if (t < 64) {
      const float pv = shF[0][t] + shF[1][t] + shF[2][t] + shF[3][t];
      const int p = b * 64 + ((y >> 3) << 3) + (t >> 3);
      const int n = ((y & 7) << 3) + (t & 7);
      posDot[p * 64 + n] = pv;
    }
  } else if (bid < 1024) {
    // ---- label mean -> flag ----
    const int p = bid - 512;
    const int b = p >> 6, pj = (p >> 3) & 7, pk = p & 7;
    const size_t base = ((size_t)b * 256 + pj * 32) * 256 + pk * 32;
    float s = 0.f;
#pragma unroll
    for (int i = 0; i < 4; ++i) {
      const int e = t * 4 + i;               // 0..1023, r=e>>5, cc=e&31
      s += label[base + (size_t)(e >> 5) * 256 + (e & 31)];
    }
#pragma unroll
    for (int d = 1; d < 64; d <<= 1) s += __shfl_xor(s, d, 64);
    if ((t & 63) == 0) shF[0][t >> 6] = s;
    __syncthreads();
    if (t == 0)
      flags[p] = ((shF[0][0] + shF[0][1] + shF[0][2] + shF[0][3]) * (1.f / 1024.f) < 0.1f) ? 1 : 0;
  } else {
    // ---- bank repack (fp8, pre-scaled by SCALE) into packed tile layout ----
    const int bb = bid - 1024;
    const float* src = (bb < 32 ? negB : posB) + (size_t)(bb & 31) * 16384;
    unsigned char* dst = (bb < 32 ? bankN : bankP) + (size_t)(bb & 31) * 16384;
#pragma unroll 8
    for (int it = 0; it < 64; ++it) {
      const int lin = it * 256 + t;          // [c][posi] linear, coalesced read
      const int c = lin >> 6, posi = lin & 63;
      shU[posi * 256 + (c ^ ((posi & 7) << 3))] = f32_to_fp8(src[lin] * SCALE);
    }
    __syncthreads();
#pragma unroll
    for (int it = 0; it < 4; ++it) {         // ct_local = it
      const int qK = (t >> 7) & 1, pair = (t >> 6) & 1;
      const int kg = (t >> 4) & 3, r16 = t & 15;
      const int posi = it * 16 + r16;
      const int kb = qK * 128 + pair * 64 + kg * 8;
      const int swz = (posi & 7) << 3;
      const unsigned long long lo = *(const unsigned long long*)&shU[posi * 256 + (kb ^ swz)];
      const unsigned long long hi = *(const unsigned long long*)&shU[posi * 256 + ((kb + 32) ^ swz)];
      long2v v; v[0] = (long)lo; v[1] = (long)hi;
      *(long2v*)(dst + it * 4096 + qK * 2048 + pair * 1024 + kg * 256 + r16 * 16) = v;
    }
  }
}

// ---------------------------------------------------------------------------
// Main kernel: grid=512 (one patch), block=256 (4 independent waves), FP8 +
// LDS-DMA staging: 8-deep per-wave LDS ring of 2 KB quarters (16 KB/wave,
// ZERO VGPR cost -> no allocator fight), global_load_lds with counted
// vmcnt(12) (14 DMAs in flight/wave). fp8 halves B-demand (26 B/cy needed vs
// the measured ~20-22 B/cy/CU delivery cap) -> staging-bound step ~820 cy.
// No barriers in the loop; per-block even phase stagger.
// ---------------------------------------------------------------------------
__global__ __launch_bounds__(256, 2) void cpl_main(
    const unsigned char* __restrict__ Apk, const float* __restrict__ posDot,
    const unsigned char* __restrict__ bankN, const unsigned char* __restrict__ bankP,
    const int* __restrict__ flags, float* __restrict__ blockSums)
{
  __shared__ __align__(1024) unsigned char Bsm[4 * 8 * 2048];   // 64 KiB
  __shared__ float swS[4][64];

  const int p = blockIdx.x;
  const int t = threadIdx.x;
  const int l = t & 63, w = t >> 6;
  const int r16 = l & 15, kg = l >> 4;
  const int qph = (p * 22) & 63;      // EVEN phase: preserves quarter parity

  const unsigned char* bankB = flags[p] ? bankP : bankN;
  const unsigned char* wsrc = bankB + (size_t)w * 131072;   // wave's 512-col stream
  unsigned char* wlds = Bsm + w * 16384;
  const int dmaOfs = l * 16;

  // ---- A fragments (fp8): lane l holds A[mt*16+r16][ks*32+kg*8 .. +7] ----
  const unsigned char* Ab = Apk + (size_t)p * 16384;
  long long afrag[4][8];
#pragma unroll
  for (int mt = 0; mt < 4; ++mt)
#pragma unroll
    for (int ks = 0; ks < 8; ++ks)
      afrag[mt][ks] = *(const long long*)(Ab + (mt * 16 + r16) * 256 + ks * 32 + kg * 8);
#pragma unroll
  for (int mt = 0; mt < 4; ++mt)
#pragma unroll
    for (int ks = 0; ks < 8; ++ks)
      asm volatile("" : "+v"(afrag[mt][ks]));

  // per-lane -pos2 init in REGISTERS (row = mt*16 + kg*4 + i)
  f32x4 negInit[4];
#pragma unroll
  for (int mt = 0; mt < 4; ++mt) {
    f32x4 v = *(const f32x4*)(posDot + (size_t)p * 64 + mt * 16 + kg * 4);
#pragma unroll
    for (int i = 0; i < 4; ++i) negInit[mt][i] = -v[i] * SCALE;
  }
#pragma unroll
  for (int mt = 0; mt < 4; ++mt) asm volatile("" : "+v"(negInit[mt]));

  // drain prologue loads so vmcnt counting below is clean
  asm volatile("s_waitcnt vmcnt(0)" ::: "memory");

#define ISSUEQ(QQ, SLOT) do {                                                      \
    const unsigned char* g_ = wsrc + (size_t)((((QQ) + qph) & 63)) * 2048 + dmaOfs;\
    unsigned char* l_ = wlds + (SLOT) * 2048;                                      \
    dma16(g_, l_);                                                                 \
    dma16(g_ + 1024, l_ + 1024);                                                   \
  } while (0)

  float s[16];
#pragma unroll
  for (int e = 0; e < 16; ++e) s[e] = 0.f;

  f32x4 acc[4];
  const unsigned char* rbase = wlds + kg * 256 + r16 * 16;

#define MFMA16(P0, P1, HALF) do {                                                  \
    if ((HALF) == 0) {                                                             \
      _Pragma("unroll") for (int mt = 0; mt < 4; ++mt)                             \
        acc[mt] = __builtin_amdgcn_mfma_f32_16x16x32_fp8_fp8(afrag[mt][0], P0[0],  \
                      negInit[mt], 0, 0, 0);                                       \
      _Pragma("unroll") for (int mt = 0; mt < 4; ++mt)                             \
        acc[mt] = __builtin_amdgcn_mfma_f32_16x16x32_fp8_fp8(afrag[mt][1], P0[1],  \
                      acc[mt], 0, 0, 0);                                           \
      _Pragma("unroll") for (int mt = 0; mt < 4; ++mt)                             \
        acc[mt] = __builtin_amdgcn_mfma_f32_16x16x32_fp8_fp8(afrag[mt][2], P1[0],  \
                      acc[mt], 0, 0, 0);                                           \
      _Pragma("unroll") for (int mt = 0; mt < 4; ++mt)                             \
        acc[mt] = __builtin_amdgcn_mfma_f32_16x16x32_fp8_fp8(afrag[mt][3], P1[1],  \
                      acc[mt], 0, 0, 0);                                           \
    } else {                                                                       \
      _Pragma("unroll") for (int mt = 0; mt < 4; ++mt)                             \
        acc[mt] = __builtin_amdgcn_mfma_f32_16x16x32_fp8_fp8(afrag[mt][4], P0[0],  \
                      acc[mt], 0, 0, 0);                                           \
      _Pragma("unroll") for (int mt = 0; mt < 4; ++mt)                             \
        acc[mt] = __builtin_amdgcn_mfma_f32_16x16x32_fp8_fp8(afrag[mt][5], P0[1],  \
                      acc[mt], 0, 0, 0);                                           \
      _Pragma("unroll") for (int mt = 0; mt < 4; ++mt)                             \
        acc[mt] = __builtin_amdgcn_mfma_f32_16x16x32_fp8_fp8(afrag[mt][6], P1[0],  \
                      acc[mt], 0, 0, 0);                                           \
      _Pragma("unroll") for (int mt = 0; mt < 4; ++mt)                             \
        acc[mt] = __builtin_amdgcn_mfma_f32_16x16x32_fp8_fp8(afrag[mt][7], P1[1],  \
                      acc[mt], 0, 0, 0);                                           \
    } } while (0)

#define EXPACC() do {                                                              \
    _Pragma("unroll") for (int mt = 0; mt < 4; ++mt)                               \
      _Pragma("unroll") for (int i = 0; i < 4; ++i)                                \
        s[mt * 4 + i] += fast_exp2(acc[mt][i]); } while (0)

  // STEP n: wait quarter n landed (vmcnt WN) -> issue quarter n+7 into the
  // slot consumed last step -> ds_read quarter n -> 16 MFMA -> EXP after odd.
#define STEP(QQ, SLOT, HALF, DO_ISSUE, WN, DO_EXP) do {                            \
    asm volatile("s_waitcnt vmcnt(" #WN ")" ::: "memory");                         \
    __builtin_amdgcn_sched_barrier(0);                                             \
    if (DO_ISSUE) ISSUEQ((QQ) + 7, ((SLOT) + 7) & 7);                              \
    { const unsigned char* rb_ = rbase + (SLOT) * 2048;                            \
      long2v P0 = *(const long2v*)rb_;                                             \
      long2v P1 = *(const long2v*)(rb_ + 1024);                                    \
      __builtin_amdgcn_s_setprio(1);                                               \
      MFMA16(P0, P1, HALF);                                                        \
      __builtin_amdgcn_s_setprio(0); }                                             \
    if (DO_EXP) EXPACC();                                                          \
    __builtin_amdgcn_sched_barrier(0);                                             \
  } while (0)

  // prologue: quarters 0..6 in flight (14 DMAs)
  ISSUEQ(0, 0); ISSUEQ(1, 1); ISSUEQ(2, 2); ISSUEQ(3, 3);
  ISSUEQ(4, 4); ISSUEQ(5, 5); ISSUEQ(6, 6);

  for (int g = 0; g < 7; ++g) {
    const int n0 = g * 8;
    STEP(n0 + 0, 0, 0, 1, 12, 0);
    STEP(n0 + 1, 1, 1, 1, 12, 1);
    STEP(n0 + 2, 2, 0, 1, 12, 0);
    STEP(n0 + 3, 3, 1, 1, 12, 1);
    STEP(n0 + 4, 4, 0, 1, 12, 0);
    STEP(n0 + 5, 5, 1, 1, 12, 1);
    STEP(n0 + 6, 6, 0, 1, 12, 0);
    STEP(n0 + 7, 7, 1, 1, 12, 1);
  }
  // tail: step 56 issues quarter 63, then drain
  STEP(56, 0, 0, 1, 12, 0);
  STEP(57, 1, 1, 0, 12, 1);
  STEP(58, 2, 0, 0, 10, 0);
  STEP(59, 3, 1, 0,  8, 1);
  STEP(60, 4, 0, 0,  6, 0);
  STEP(61, 5, 1, 0,  4, 1);
  STEP(62, 6, 0, 0,  2, 0);
  STEP(63, 7, 1, 0,  0, 1);

#undef STEP
#undef EXPACC
#undef MFMA16
#undef ISSUEQ

  // ---- sum the 16 column-partials (lanes differing in low 4 bits) ----
#pragma unroll
  for (int d = 1; d < 16; d <<= 1)
#pragma unroll
    for (int e = 0; e < 16; ++e) s[e] += __shfl_xor(s[e], d, 64);
  if (r16 == 0) {
#pragma unroll
    for (int mt = 0; mt < 4; ++mt)
#pragma unroll
      for (int i = 0; i < 4; ++i)
        swS[w][mt * 16 + kg * 4 + i] = s[mt * 4 + i];
  }
  __syncthreads();

  // ---- final per-row loss + block reduce (wave 0 only) ----
  if (t < 64) {
    const float S = 1.f + swS[0][t] + swS[1][t] + swS[2][t] + swS[3][t];
    float loss = -logf(1.f / S + EPSV);
#pragma unroll
    for (int d = 1; d < 64; d <<= 1) loss += __shfl_xor(loss, d, 64);
    if (t == 0) blockSums[p] = loss;
  }
}

// ---------------------------------------------------------------------------
// Final: mean of 512 block sums / (512*64).  grid=1, block=256.
// ---------------------------------------------------------------------------
__global__ void cpl_final(const float* __restrict__ blockSums, float* __restrict__ out) {
  const int t = threadIdx.x;
  float s = blockSums[t] + blockSums[t + 256];
#pragma unroll
  for (int d = 1; d < 64; d <<= 1) s += __shfl_xor(s, d, 64);
  __shared__ float ps[4];
  if ((t & 63) == 0) ps[t >> 6] = s;
  __syncthreads();
  if (t == 0) out[0] = (ps[0] + ps[1] + ps[2] + ps[3]) * (1.f / 32768.f);
}

extern "C" void kernel_launch(void* const* d_in, const int* in_sizes, int n_in,
                              void* d_out, int out_size, void* d_ws, size_t ws_size,
                              hipStream_t stream) {
  const float* mainO = (const float*)d_in[0];
  const float* emaO  = (const float*)d_in[1];
  const float* label = (const float*)d_in[2];
  const float* negB  = (const float*)d_in[3];
  const float* posB  = (const float*)d_in[4];
  float* out = (float*)d_out;

  char* ws = (char*)d_ws;
  float*         blockSums = (float*)ws;                          // 2 KiB
  int*           flags     = (int*)(ws + 2048);                   // 2 KiB
  unsigned char* bankN     = (unsigned char*)(ws + 4096);         // 512 KiB
  unsigned char* bankP     = (unsigned char*)(ws + 528384);       // 512 KiB
  float*         posDot    = (float*)(ws + 1052672);              // 128 KiB
  unsigned char* Apk       = (unsigned char*)(ws + 1183744);      // 8 MiB

  hipLaunchKernelGGL(cpl_prep, dim3(1088), dim3(256), 0, stream,
                     mainO, emaO, label, negB, posB, Apk, posDot, flags, bankN, bankP);
  hipLaunchKernelGGL(cpl_main, dim3(512), dim3(256), 0, stream,
                     Apk, posDot, bankN, bankP, flags, blockSums);
  hipLaunchKernelGGL(cpl_final, dim3(1), dim3(256), 0, stream, blockSums, out);
}

// Round 19
// 49.458 us; speedup vs baseline: 1.7124x; 1.0718x over previous
//
#include <hip/hip_runtime.h>

typedef __attribute__((ext_vector_type(2))) long long2v;
typedef __attribute__((ext_vector_type(4))) float f32x4;

#define EPSV 1e-5f
// (1/TEMP) * log2(e),  TEMP = 0.5  -> exp2-domain scale
#define SCALE 2.885390081777927f

// Must be the builtin — raw inline-asm v_exp_f32 lacks the TRANS-pipe hazard
// nop (asm is opaque to the hazard recognizer) and returns garbage (R4).
__device__ __forceinline__ float fast_exp2(float x) { return __builtin_amdgcn_exp2f(x); }

// f32 -> OCP e4m3fn byte (hardware converter; saturates at +-448)
__device__ __forceinline__ unsigned char f32_to_fp8(float f) {
  return (unsigned char)(__builtin_amdgcn_cvt_pk_fp8_f32(f, f, 0, false) & 0xff);
}

// ---------------------------------------------------------------------------
// FP8 packed bank layout (pre-scaled by SCALE):
//   quarter q (2 KB) = (ct = q>>1, qK = q&1); lane (kg,r16) reads 16 B at
//   q*2048 + pair*1024 + kg*256 + r16*16 holding B-frags ks=2*pair, 2*pair+1.
// Apk (fp8 anchors): byte = p*16384 + row*256 + k.
// ---------------------------------------------------------------------------

// ---------------------------------------------------------------------------
// Fused prep kernel, grid = 512 + 512 + 64 = 1088 blocks, 256 threads.
// ---------------------------------------------------------------------------
__global__ __launch_bounds__(256) void cpl_prep(
    const float* __restrict__ mainO, const float* __restrict__ emaO,
    const float* __restrict__ label, const float* __restrict__ negB,
    const float* __restrict__ posB,
    unsigned char* __restrict__ Apk, float* __restrict__ posDot,
    int* __restrict__ flags, unsigned char* __restrict__ bankN,
    unsigned char* __restrict__ bankP)
{
  __shared__ __align__(16) unsigned char shU[64 * 256];   // 16 KiB
  __shared__ float shF[4][64];
  const int bid = blockIdx.x;
  const int t = threadIdx.x;

  if (bid < 512) {
    // ---- anchor pack (fp8) + pos dot: block = (b, y) ----
    const int b = bid >> 6, y = bid & 63;
    const int cg = t >> 4;            // c-offset 0..15
    const int x4 = t & 15;            // float4 index along W
    const float* mB = mainO + (((size_t)b * 256 + cg) * 64 + y) * 64 + x4 * 4;
    const float* eB = emaO  + (((size_t)b * 256 + cg) * 64 + y) * 64 + x4 * 4;
    float4 acc4 = make_float4(0.f, 0.f, 0.f, 0.f);
#pragma unroll
    for (int pass = 0; pass < 16; ++pass) {
      const int c = pass * 16 + cg;
      const float4 mv = *(const float4*)(mB + (size_t)pass * 16 * 4096);
      const float4 ev = *(const float4*)(eB + (size_t)pass * 16 * 4096);
      acc4.x += mv.x * ev.x; acc4.y += mv.y * ev.y;
      acc4.z += mv.z * ev.z; acc4.w += mv.w * ev.w;
      const float vals[4] = {mv.x, mv.y, mv.z, mv.w};
#pragma unroll
      for (int j = 0; j < 4; ++j) {
        const int x = x4 * 4 + j;
        shU[x * 256 + (c ^ ((x & 7) << 4))] = f32_to_fp8(vals[j]);
      }
    }
    // reduce pos partials over c-groups (cg bit0 = lane bit4, bit1 = lane bit5)
    acc4.x += __shfl_xor(acc4.x, 16, 64); acc4.y += __shfl_xor(acc4.y, 16, 64);
    acc4.z += __shfl_xor(acc4.z, 16, 64); acc4.w += __shfl_xor(acc4.w, 16, 64);
    acc4.x += __shfl_xor(acc4.x, 32, 64); acc4.y += __shfl_xor(acc4.y, 32, 64);
    acc4.z += __shfl_xor(acc4.z, 32, 64); acc4.w += __shfl_xor(acc4.w, 32, 64);
    if ((t & 63) < 16) *(float4*)&shF[t >> 6][(t & 15) * 4] = acc4;
    __syncthreads();
    // write packed fp8 anchors (coalesced b128)
#pragma unroll
    for (int it = 0; it < 4; ++it) {
      const int lin = it * 256 + t;          // 0..1023
      const int x = lin >> 4, c16 = lin & 15;
      const uint4 v = *(const uint4*)&shU[x * 256 + ((c16 * 16) ^ ((x & 7) << 4))];
      const int p = b * 64 + ((y >> 3) << 3) + (x >> 3);
      const int n = ((y & 7) << 3) + (x & 7);
      *(uint4*)&Apk[(size_t)p * 16384 + n * 256 + c16 * 16] = v;
    }
    if (t < 64) {
      const float pv = shF[0][t] + shF[1][t] + shF[2][t] + shF[3][t];
      const int p = b * 64 + ((y >> 3) << 3) + (t >> 3);
      const int n = ((y & 7) << 3) + (t & 7);
      posDot[p * 64 + n] = pv;
    }
  } else if (bid < 1024) {
    // ---- label mean -> flag ----
    const int p = bid - 512;
    const int b = p >> 6, pj = (p >> 3) & 7, pk = p & 7;
    const size_t base = ((size_t)b * 256 + pj * 32) * 256 + pk * 32;
    float s = 0.f;
#pragma unroll
    for (int i = 0; i < 4; ++i) {
      const int e = t * 4 + i;               // 0..1023, r=e>>5, cc=e&31
      s += label[base + (size_t)(e >> 5) * 256 + (e & 31)];
    }
#pragma unroll
    for (int d = 1; d < 64; d <<= 1) s += __shfl_xor(s, d, 64);
    if ((t & 63) == 0) shF[0][t >> 6] = s;
    __syncthreads();
    if (t == 0)
      flags[p] = ((shF[0][0] + shF[0][1] + shF[0][2] + shF[0][3]) * (1.f / 1024.f) < 0.1f) ? 1 : 0;
  } else {
    // ---- bank repack (fp8, pre-scaled by SCALE) into packed tile layout ----
    const int bb = bid - 1024;
    const float* src = (bb < 32 ? negB : posB) + (size_t)(bb & 31) * 16384;
    unsigned char* dst = (bb < 32 ? bankN : bankP) + (size_t)(bb & 31) * 16384;
#pragma unroll 8
    for (int it = 0; it < 64; ++it) {
      const int lin = it * 256 + t;          // [c][posi] linear, coalesced read
      const int c = lin >> 6, posi = lin & 63;
      shU[posi * 256 + (c ^ ((posi & 7) << 3))] = f32_to_fp8(src[lin] * SCALE);
    }
    __syncthreads();
#pragma unroll
    for (int it = 0; it < 4; ++it) {         // ct_local = it
      const int qK = (t >> 7) & 1, pair = (t >> 6) & 1;
      const int kg = (t >> 4) & 3, r16 = t & 15;
      const int posi = it * 16 + r16;
      const int kb = qK * 128 + pair * 64 + kg * 8;
      const int swz = (posi & 7) << 3;
      const unsigned long long lo = *(const unsigned long long*)&shU[posi * 256 + (kb ^ swz)];
      const unsigned long long hi = *(const unsigned long long*)&shU[posi * 256 + ((kb + 32) ^ swz)];
      long2v v; v[0] = (long)lo; v[1] = (long)hi;
      *(long2v*)(dst + it * 4096 + qK * 2048 + pair * 1024 + kg * 256 + r16 * 16) = v;
    }
  }
}

// ---------------------------------------------------------------------------
// Main kernel: grid=512 (one patch), block=256 (4 independent waves), FP8.
// B streamed directly to registers (2 x dwordx4 per 2 KB quarter) through an
// 8-DEEP register ring (14 loads in flight -> latency term L/7); MFMA
// 16x16x32_fp8_fp8 (bf16 rate, half the operand bytes -> 2x arithmetic
// intensity vs bf16 against the measured ~22 B/cy/CU B-delivery ceiling).
// Best-measured configuration (R14: 49.1 us total).
// ---------------------------------------------------------------------------
__global__ __launch_bounds__(256, 2) void cpl_main(
    const unsigned char* __restrict__ Apk, const float* __restrict__ posDot,
    const unsigned char* __restrict__ bankN, const unsigned char* __restrict__ bankP,
    const int* __restrict__ flags, float* __restrict__ blockSums)
{
  __shared__ float swS[4][64];

  const int p = blockIdx.x;
  const int t = threadIdx.x;
  const int l = t & 63, w = t >> 6;
  const int r16 = l & 15, kg = l >> 4;
  const int qph = (p * 22) & 63;      // EVEN phase: preserves quarter parity

  const unsigned char* bankB = flags[p] ? bankP : bankN;
  const unsigned char* wsrc = bankB + (size_t)w * 131072;   // wave's 512-col stream
  const int lofs = kg * 256 + r16 * 16;

  // ---- A fragments (fp8): lane l holds A[mt*16+r16][ks*32+kg*8 .. +7] ----
  const unsigned char* Ab = Apk + (size_t)p * 16384;
  long long afrag[4][8];
#pragma unroll
  for (int mt = 0; mt < 4; ++mt)
#pragma unroll
    for (int ks = 0; ks < 8; ++ks)
      afrag[mt][ks] = *(const long long*)(Ab + (mt * 16 + r16) * 256 + ks * 32 + kg * 8);
#pragma unroll
  for (int mt = 0; mt < 4; ++mt)
#pragma unroll
    for (int ks = 0; ks < 8; ++ks)
      asm volatile("" : "+v"(afrag[mt][ks]));

  // per-lane -pos2 init in REGISTERS (row = mt*16 + kg*4 + i)
  f32x4 negInit[4];
#pragma unroll
  for (int mt = 0; mt < 4; ++mt) {
    f32x4 v = *(const f32x4*)(posDot + (size_t)p * 64 + mt * 16 + kg * 4);
#pragma unroll
    for (int i = 0; i < 4; ++i) negInit[mt][i] = -v[i] * SCALE;
  }
#pragma unroll
  for (int mt = 0; mt < 4; ++mt) asm volatile("" : "+v"(negInit[mt]));

  float s[16];
#pragma unroll
  for (int e = 0; e < 16; ++e) s[e] = 0.f;

  f32x4 acc[4];
  long2v A0, A1, B0, B1, C0, C1, D0, D1, E0, E1, F0, F1, G0, G1, H0, H1;

#define GLOAD(P0, P1, QQ) do {                                                     \
    const unsigned char* g_ = wsrc + (size_t)((((QQ) + qph) & 63)) * 2048 + lofs;  \
    P0 = *(const long2v*)g_;                                                       \
    P1 = *(const long2v*)(g_ + 1024);                                              \
  } while (0)

#define MFMA16(P0, P1, HALF) do {                                                  \
    if ((HALF) == 0) {                                                             \
      _Pragma("unroll") for (int mt = 0; mt < 4; ++mt)                             \
        acc[mt] = __builtin_amdgcn_mfma_f32_16x16x32_fp8_fp8(afrag[mt][0], P0[0],  \
                      negInit[mt], 0, 0, 0);                                       \
      _Pragma("unroll") for (int mt = 0; mt < 4; ++mt)                             \
        acc[mt] = __builtin_amdgcn_mfma_f32_16x16x32_fp8_fp8(afrag[mt][1], P0[1],  \
                      acc[mt], 0, 0, 0);                                           \
      _Pragma("unroll") for (int mt = 0; mt < 4; ++mt)                             \
        acc[mt] = __builtin_amdgcn_mfma_f32_16x16x32_fp8_fp8(afrag[mt][2], P1[0],  \
                      acc[mt], 0, 0, 0);                                           \
      _Pragma("unroll") for (int mt = 0; mt < 4; ++mt)                             \
        acc[mt] = __builtin_amdgcn_mfma_f32_16x16x32_fp8_fp8(afrag[mt][3], P1[1],  \
                      acc[mt], 0, 0, 0);                                           \
    } else {                                                                       \
      _Pragma("unroll") for (int mt = 0; mt < 4; ++mt)                             \
        acc[mt] = __builtin_amdgcn_mfma_f32_16x16x32_fp8_fp8(afrag[mt][4], P0[0],  \
                      acc[mt], 0, 0, 0);                                           \
      _Pragma("unroll") for (int mt = 0; mt < 4; ++mt)                             \
        acc[mt] = __builtin_amdgcn_mfma_f32_16x16x32_fp8_fp8(afrag[mt][5], P0[1],  \
                      acc[mt], 0, 0, 0);                                           \
      _Pragma("unroll") for (int mt = 0; mt < 4; ++mt)                             \
        acc[mt] = __builtin_amdgcn_mfma_f32_16x16x32_fp8_fp8(afrag[mt][6], P1[0],  \
                      acc[mt], 0, 0, 0);                                           \
      _Pragma("unroll") for (int mt = 0; mt < 4; ++mt)                             \
        acc[mt] = __builtin_amdgcn_mfma_f32_16x16x32_fp8_fp8(afrag[mt][7], P1[1],  \
                      acc[mt], 0, 0, 0);                                           \
    } } while (0)

#define EXPACC() do {                                                              \
    _Pragma("unroll") for (int mt = 0; mt < 4; ++mt)                               \
      _Pragma("unroll") for (int i = 0; i < 4; ++i)                                \
        s[mt * 4 + i] += fast_exp2(acc[mt][i]); } while (0)

  // STEP n: load quarter n+7 into the buffer consumed last step; MFMA on the
  // buffer loaded 7 steps ago (compiler emits counted vmcnt); EXP after odd.
#define STEP(QQ, U0, U1, L0, L1, HALF, DO_LOAD, DO_EXP) do {                       \
    if (DO_LOAD) GLOAD(L0, L1, (QQ) + 7);                                          \
    __builtin_amdgcn_sched_barrier(0);                                             \
    __builtin_amdgcn_s_setprio(1);                                                 \
    MFMA16(U0, U1, HALF);                                                          \
    __builtin_amdgcn_s_setprio(0);                                                 \
    if (DO_EXP) EXPACC();                                                          \
    __builtin_amdgcn_sched_barrier(0);                                             \
  } while (0)

  // prologue: quarters 0..6 in flight (14 loads)
  GLOAD(A0, A1, 0); GLOAD(B0, B1, 1); GLOAD(C0, C1, 2); GLOAD(D0, D1, 3);
  GLOAD(E0, E1, 4); GLOAD(F0, F1, 5); GLOAD(G0, G1, 6);

  for (int g = 0; g < 7; ++g) {
    const int n0 = g * 8;
    STEP(n0 + 0, A0, A1, H0, H1, 0, 1, 0);
    STEP(n0 + 1, B0, B1, A0, A1, 1, 1, 1);
    STEP(n0 + 2, C0, C1, B0, B1, 0, 1, 0);
    STEP(n0 + 3, D0, D1, C0, C1, 1, 1, 1);
    STEP(n0 + 4, E0, E1, D0, D1, 0, 1, 0);
    STEP(n0 + 5, F0, F1, E0, E1, 1, 1, 1);
    STEP(n0 + 6, G0, G1, F0, F1, 0, 1, 0);
    STEP(n0 + 7, H0, H1, G0, G1, 1, 1, 1);
  }
  // final group: step 56 loads quarter 63, then drain
  STEP(56, A0, A1, H0, H1, 0, 1, 0);
  STEP(57, B0, B1, A0, A1, 1, 0, 1);
  STEP(58, C0, C1, B0, B1, 0, 0, 0);
  STEP(59, D0, D1, C0, C1, 1, 0, 1);
  STEP(60, E0, E1, D0, D1, 0, 0, 0);
  STEP(61, F0, F1, E0, E1, 1, 0, 1);
  STEP(62, G0, G1, F0, F1, 0, 0, 0);
  STEP(63, H0, H1, G0, G1, 1, 0, 1);

#undef STEP
#undef EXPACC
#undef MFMA16
#undef GLOAD

  // ---- sum the 16 column-partials (lanes differing in low 4 bits) ----
#pragma unroll
  for (int d = 1; d < 16; d <<= 1)
#pragma unroll
    for (int e = 0; e < 16; ++e) s[e] += __shfl_xor(s[e], d, 64);
  if (r16 == 0) {
#pragma unroll
    for (int mt = 0; mt < 4; ++mt)
#pragma unroll
      for (int i = 0; i < 4; ++i)
        swS[w][mt * 16 + kg * 4 + i] = s[mt * 4 + i];
  }
  __syncthreads();

  // ---- final per-row loss + block reduce (wave 0 only) ----
  if (t < 64) {
    const float S = 1.f + swS[0][t] + swS[1][t] + swS[2][t] + swS[3][t];
    float loss = -logf(1.f / S + EPSV);
#pragma unroll
    for (int d = 1; d < 64; d <<= 1) loss += __shfl_xor(loss, d, 64);
    if (t == 0) blockSums[p] = loss;
  }
}

// ---------------------------------------------------------------------------
// Final: mean of 512 block sums / (512*64).  grid=1, block=256.
// ---------------------------------------------------------------------------
__global__ void cpl_final(const float* __restrict__ blockSums, float* __restrict__ out) {
  const int t = threadIdx.x;
  float s = blockSums[t] + blockSums[t + 256];
#pragma unroll
  for (int d = 1; d < 64; d <<= 1) s += __shfl_xor(s, d, 64);
  __shared__ float ps[4];
  if ((t & 63) == 0) ps[t >> 6] = s;
  __syncthreads();
  if (t == 0) out[0] = (ps[0] + ps[1] + ps[2] + ps[3]) * (1.f / 32768.f);
}

extern "C" void kernel_launch(void* const* d_in, const int* in_sizes, int n_in,
                              void* d_out, int out_size, void* d_ws, size_t ws_size,
                              hipStream_t stream) {
  const float* mainO = (const float*)d_in[0];
  const float* emaO  = (const float*)d_in[1];
  const float* label = (const float*)d_in[2];
  const float* negB  = (const float*)d_in[3];
  const float* posB  = (const float*)d_in[4];
  float* out = (float*)d_out;

  char* ws = (char*)d_ws;
  float*         blockSums = (float*)ws;                          // 2 KiB
  int*           flags     = (int*)(ws + 2048);                   // 2 KiB
  unsigned char* bankN     = (unsigned char*)(ws + 4096);         // 512 KiB
  unsigned char* bankP     = (unsigned char*)(ws + 528384);       // 512 KiB
  float*         posDot    = (float*)(ws + 1052672);              // 128 KiB
  unsigned char* Apk       = (unsigned char*)(ws + 1183744);      // 8 MiB

  hipLaunchKernelGGL(cpl_prep, dim3(1088), dim3(256), 0, stream,
                     mainO, emaO, label, negB, posB, Apk, posDot, flags, bankN, bankP);
  hipLaunchKernelGGL(cpl_main, dim3(512), dim3(256), 0, stream,
                     Apk, posDot, bankN, bankP, flags, blockSums);
  hipLaunchKernelGGL(cpl_final, dim3(1), dim3(256), 0, stream, blockSums, out);
}